// Round 2
// baseline (466.064 us; speedup 1.0000x reference)
//
#include <hip/hip_runtime.h>

// AdderNet LeNet forward on MI355X.
// Pipeline:
//   prep_weights: pad w1/w2 kernel rows 5->8 floats (16B-aligned rows)
//   layer1: adder-conv(C=1) + PReLU -> h1pad [256][32][28][28] (zero-padded
//           layout: h1pad[b][o][pr][pc] = h1[b][o][pr-2][pc-2], pad = 0)
//   layer2_fused: adder-conv(C=32) + PReLU + 3x maxpool + ip1(PReLU) + ip2
//           -> d_out (ip1 [256,2] then ip2 [256,10], flat)
// Only h2 rows/cols 0..23 survive the pool chain -> compute 24x24 only.

// ---------------- weight prep ----------------
// wpad1[o][kh][8], wpad2[o][c][kh][8]
__global__ void prep_weights(const float* __restrict__ w1,
                             const float* __restrict__ w2,
                             float* __restrict__ wpad1,
                             float* __restrict__ wpad2) {
    int tid = threadIdx.x + blockIdx.x * blockDim.x;
    int stride = blockDim.x * gridDim.x;
    for (int i = tid; i < 32 * 5 * 8; i += stride) {
        int kw = i & 7, kh = (i >> 3) % 5, o = i / 40;
        wpad1[i] = (kw < 5) ? w1[o * 25 + kh * 5 + kw] : 0.f;
    }
    for (int i = tid; i < 32 * 32 * 5 * 8; i += stride) {
        int kw = i & 7, kh = (i >> 3) % 5, oc = i / 40;
        wpad2[i] = (kw < 5) ? w2[oc * 25 + kh * 5 + kw] : 0.f;
    }
}

// ---------------- layer 1 ----------------
// block = one batch element b; 896 threads = 32 o x 28 r tasks.
// Threads r<26 compute output row r (26 cols) and write padded row pr=r+2.
// Threads r=26,27 write zero rows pr=0,1. All 28 padded rows covered.
__global__ __launch_bounds__(896) void layer1(const float* __restrict__ x,
                                              const float* __restrict__ wpad1,
                                              const float* __restrict__ a1v,
                                              float* __restrict__ h1pad) {
    __shared__ float lx[32 * 32];  // x[b] padded by 2 (orig -2..29)
    const int b = blockIdx.x;
    const int tid = threadIdx.x;

    for (int i = tid; i < 32 * 32; i += 896) {
        int pr = i >> 5, pc = i & 31;
        int r = pr - 2, c = pc - 2;
        float v = 0.f;
        if (r >= 0 && r < 28 && c >= 0 && c < 28) v = x[b * 784 + r * 28 + c];
        lx[i] = v;
    }
    __syncthreads();

    const int o = tid / 28, r = tid % 28;
    float* orow = h1pad + (size_t)(b * 32 + o) * 784;

    if (r >= 26) {
        // zero-pad rows pr = 0,1
        float4 z = {0.f, 0.f, 0.f, 0.f};
        float4* dst = (float4*)(orow + (r - 26) * 28);
#pragma unroll
        for (int i = 0; i < 7; i++) dst[i] = z;
        return;
    }

    float acc[26];
#pragma unroll
    for (int j = 0; j < 26; j++) acc[j] = 0.f;

    const float* wb = wpad1 + o * 40;
#pragma unroll
    for (int kh = 0; kh < 5; kh++) {
        const float4* xr = (const float4*)&lx[(r + kh) * 32];
        float xw[32];
#pragma unroll
        for (int i = 0; i < 8; i++) {
            float4 v = xr[i];
            xw[4 * i + 0] = v.x; xw[4 * i + 1] = v.y;
            xw[4 * i + 2] = v.z; xw[4 * i + 3] = v.w;
        }
        float4 W0 = *(const float4*)(wb + kh * 8);
        float w4 = (wb + kh * 8)[4];
        float wv[5] = {W0.x, W0.y, W0.z, W0.w, w4};
#pragma unroll
        for (int kw = 0; kw < 5; kw++)
#pragma unroll
            for (int j = 0; j < 26; j++)
                acc[j] += fabsf(xw[j + kw] - wv[kw]);
    }

    const float alpha = a1v[0];
    float outv[28];
    outv[0] = 0.f; outv[1] = 0.f;
#pragma unroll
    for (int j = 0; j < 26; j++) {
        float v = -acc[j];
        outv[j + 2] = (v >= 0.f) ? v : alpha * v;
    }
    float4* dst = (float4*)(orow + (r + 2) * 28);
#pragma unroll
    for (int i = 0; i < 7; i++) {
        float4 v = {outv[4 * i], outv[4 * i + 1], outv[4 * i + 2], outv[4 * i + 3]};
        dst[i] = v;
    }
}

// ---------------- layer 2 + pool + FC (fused) ----------------
// block = one batch element; 768 threads = 32 o x 24 r tasks.
__global__ __launch_bounds__(768) void layer2_fused(
    const float* __restrict__ h1pad, const float* __restrict__ wpad2,
    const float* __restrict__ a2v, const float* __restrict__ ip1_w,
    const float* __restrict__ ip1_b, const float* __restrict__ a3v,
    const float* __restrict__ ip2_w, float* __restrict__ dout) {
    __shared__ float lx[32 * 28 * 28];   // 100352 B, h1pad[b]
    __shared__ float lrm[32 * 24 * 3];   // per-(o,row) maxes over col-octets
    __shared__ float lpool[288];         // pooled [32][3][3] flat

    const int b = blockIdx.x, tid = threadIdx.x;

    {   // stage h1pad[b] -> LDS (25088 floats, coalesced float4)
        const float4* src = (const float4*)(h1pad + (size_t)b * 25088);
        float4* dst = (float4*)lx;
        for (int i = tid; i < 6272; i += 768) dst[i] = src[i];
    }
    __syncthreads();

    const int o = tid / 24, r = tid % 24;
    float acc[24];
#pragma unroll
    for (int j = 0; j < 24; j++) acc[j] = 0.f;

    const float* wb = wpad2 + o * (32 * 40);
    for (int c = 0; c < 32; c++) {
#pragma unroll
        for (int kh = 0; kh < 5; kh++) {
            const float4* xr = (const float4*)&lx[(c * 28 + r + kh) * 28];
            float xw[28];
#pragma unroll
            for (int i = 0; i < 7; i++) {
                float4 v = xr[i];
                xw[4 * i + 0] = v.x; xw[4 * i + 1] = v.y;
                xw[4 * i + 2] = v.z; xw[4 * i + 3] = v.w;
            }
            const float* wrow = wb + (c * 5 + kh) * 8;
            float4 W0 = *(const float4*)wrow;
            float w4 = wrow[4];
            float wv[5] = {W0.x, W0.y, W0.z, W0.w, w4};
#pragma unroll
            for (int kw = 0; kw < 5; kw++)
#pragma unroll
                for (int j = 0; j < 24; j++)
                    acc[j] += fabsf(xw[j + kw] - wv[kw]);
        }
    }

    // PReLU + horizontal pool (max over col-octets)
    const float alpha = a2v[0];
#pragma unroll
    for (int jj = 0; jj < 3; jj++) {
        float m = -1e30f;
#pragma unroll
        for (int k = 0; k < 8; k++) {
            float v = -acc[jj * 8 + k];
            v = (v >= 0.f) ? v : alpha * v;
            m = fmaxf(m, v);
        }
        lrm[(o * 24 + r) * 3 + jj] = m;
    }
    __syncthreads();

    // vertical pool: max over row-octets -> pooled[o][i][j]
    if (tid < 288) {
        int oo = tid / 9, rem = tid % 9, ii = rem / 3, jj = rem % 3;
        float m = -1e30f;
#pragma unroll
        for (int k = 0; k < 8; k++)
            m = fmaxf(m, lrm[(oo * 24 + ii * 8 + k) * 3 + jj]);
        lpool[tid] = m;  // tid == oo*9 + ii*3 + jj == flatten index
    }
    __syncthreads();

    // FC head on wave 0: ip1 = prelu(pooled @ ip1_w.T + b), ip2 = ip1 @ ip2_w.T
    if (tid < 64) {
        float f0 = 0.f, f1 = 0.f;
        for (int t = tid; t < 288; t += 64) {
            float p = lpool[t];
            f0 += p * ip1_w[t];
            f1 += p * ip1_w[288 + t];
        }
#pragma unroll
        for (int off = 32; off > 0; off >>= 1) {
            f0 += __shfl_down(f0, off);
            f1 += __shfl_down(f1, off);
        }
        if (tid == 0) {
            float a3 = a3v[0];
            float i0 = f0 + ip1_b[0], i1 = f1 + ip1_b[1];
            i0 = (i0 >= 0.f) ? i0 : a3 * i0;
            i1 = (i1 >= 0.f) ? i1 : a3 * i1;
            dout[b * 2 + 0] = i0;
            dout[b * 2 + 1] = i1;
#pragma unroll
            for (int m = 0; m < 10; m++)
                dout[512 + b * 10 + m] = i0 * ip2_w[m * 2] + i1 * ip2_w[m * 2 + 1];
        }
    }
}

extern "C" void kernel_launch(void* const* d_in, const int* in_sizes, int n_in,
                              void* d_out, int out_size, void* d_ws, size_t ws_size,
                              hipStream_t stream) {
    const float* x     = (const float*)d_in[0];
    const float* w1    = (const float*)d_in[1];
    const float* a1    = (const float*)d_in[2];
    const float* w2    = (const float*)d_in[3];
    const float* a2    = (const float*)d_in[4];
    const float* ip1_w = (const float*)d_in[5];
    const float* ip1_b = (const float*)d_in[6];
    const float* a3    = (const float*)d_in[7];
    const float* ip2_w = (const float*)d_in[8];
    float* out = (float*)d_out;

    char* ws = (char*)d_ws;
    float* wpad1 = (float*)(ws);                 //   5120 B
    float* wpad2 = (float*)(ws + 8192);          // 163840 B
    float* h1pad = (float*)(ws + 262144);        // 25.69 MB

    prep_weights<<<40, 512, 0, stream>>>(w1, w2, wpad1, wpad2);
    layer1<<<256, 896, 0, stream>>>(x, wpad1, a1, h1pad);
    layer2_fused<<<256, 768, 0, stream>>>(h1pad, wpad2, a2, ip1_w, ip1_b, a3,
                                          ip2_w, out);
}

// Round 4
// 433.742 us; speedup vs baseline: 1.0745x; 1.0745x over previous
//
#include <hip/hip_runtime.h>

// AdderNet LeNet forward on MI355X — round 3 (resubmit; round-3 bench was an
// infra timeout, no data).
// Changes vs round 2 (which was latency-bound: true VALU ~27%, 3-way LDS
// bank conflicts, in-loop scattered global weight loads):
//  - lane->o mapping (o=tid&31): LDS x-row reads become 2-address
//    broadcasts across half-waves -> conflict-free (row stride 28 dwords,
//    quads {b..b+3} and {b+28..b+31} disjoint mod 32).
//  - weights pre-transposed to [c][kh][kw][o]: the 25 per-c weight loads
//    are single-line coalesced/broadcast, hoisted out of the kh/kw loop.

// wt1: [5][5][32]  = [kh][kw][o]
// wt2: [32][5][5][32] = [c][kh][kw][o]
__global__ void prep_weights(const float* __restrict__ w1,
                             const float* __restrict__ w2,
                             float* __restrict__ wt1,
                             float* __restrict__ wt2) {
    int tid = threadIdx.x + blockIdx.x * blockDim.x;
    int stride = blockDim.x * gridDim.x;
    for (int i = tid; i < 5 * 5 * 32; i += stride) {
        int o = i & 31, kw = (i >> 5) % 5, kh = i / 160;
        wt1[i] = w1[o * 25 + kh * 5 + kw];
    }
    for (int i = tid; i < 32 * 5 * 5 * 32; i += stride) {
        int o = i & 31, kw = (i >> 5) % 5, kh = ((i >> 5) / 5) % 5, c = i / 800;
        wt2[i] = w2[o * 800 + c * 25 + kh * 5 + kw];
    }
}

// ---------------- layer 1 ----------------
// block = one batch element; 896 threads: o = tid&31, r = tid>>5 (0..27).
// r<26 compute h1 row r -> padded row r+2; r=26,27 write zero pad rows 0,1.
__global__ __launch_bounds__(896) void layer1(const float* __restrict__ x,
                                              const float* __restrict__ wt1,
                                              const float* __restrict__ a1v,
                                              float* __restrict__ h1pad) {
    __shared__ float lx[32 * 32];  // x[b] padded by 2 (orig -2..29)
    const int b = blockIdx.x;
    const int tid = threadIdx.x;

    for (int i = tid; i < 32 * 32; i += 896) {
        int pr = i >> 5, pc = i & 31;
        int r = pr - 2, c = pc - 2;
        float v = 0.f;
        if (r >= 0 && r < 28 && c >= 0 && c < 28) v = x[b * 784 + r * 28 + c];
        lx[i] = v;
    }
    __syncthreads();

    const int o = tid & 31, r = tid >> 5;
    float* orow = h1pad + (size_t)(b * 32 + o) * 784;

    if (r >= 26) {
        float4 z = {0.f, 0.f, 0.f, 0.f};
        float4* dst = (float4*)(orow + (r - 26) * 28);
#pragma unroll
        for (int i = 0; i < 7; i++) dst[i] = z;
        return;
    }

    // 25 coalesced weight loads (lane o -> consecutive floats)
    float wv[25];
    const float* wp = wt1 + o;
#pragma unroll
    for (int k = 0; k < 25; k++) wv[k] = wp[k * 32];

    float acc[26];
#pragma unroll
    for (int j = 0; j < 26; j++) acc[j] = 0.f;

#pragma unroll
    for (int kh = 0; kh < 5; kh++) {
        const float4* xr = (const float4*)&lx[(r + kh) * 32];
        float xw[32];
#pragma unroll
        for (int i = 0; i < 8; i++) {
            float4 v = xr[i];
            xw[4 * i + 0] = v.x; xw[4 * i + 1] = v.y;
            xw[4 * i + 2] = v.z; xw[4 * i + 3] = v.w;
        }
#pragma unroll
        for (int kw = 0; kw < 5; kw++)
#pragma unroll
            for (int j = 0; j < 26; j++)
                acc[j] += fabsf(xw[j + kw] - wv[kh * 5 + kw]);
    }

    const float alpha = a1v[0];
    float outv[28];
    outv[0] = 0.f; outv[1] = 0.f;
#pragma unroll
    for (int j = 0; j < 26; j++) {
        float v = -acc[j];
        outv[j + 2] = (v >= 0.f) ? v : alpha * v;
    }
    float4* dst = (float4*)(orow + (r + 2) * 28);
#pragma unroll
    for (int i = 0; i < 7; i++) {
        float4 v = {outv[4 * i], outv[4 * i + 1], outv[4 * i + 2], outv[4 * i + 3]};
        dst[i] = v;
    }
}

// ---------------- layer 2 + pool + FC (fused) ----------------
// block = one batch element; 768 threads: o = tid&31, r = tid>>5 (0..23).
__global__ __launch_bounds__(768, 3) void layer2_fused(
    const float* __restrict__ h1pad, const float* __restrict__ wt2,
    const float* __restrict__ a2v, const float* __restrict__ ip1_w,
    const float* __restrict__ ip1_b, const float* __restrict__ a3v,
    const float* __restrict__ ip2_w, float* __restrict__ dout) {
    __shared__ float lx[32 * 28 * 28];   // 100352 B, h1pad[b]
    __shared__ float lrm[32 * 24 * 3];   // per-(o,row) maxes over col-octets
    __shared__ float lpool[288];         // pooled [32][3][3] flat

    const int b = blockIdx.x, tid = threadIdx.x;

    {   // stage h1pad[b] -> LDS (coalesced float4)
        const float4* src = (const float4*)(h1pad + (size_t)b * 25088);
        float4* dst = (float4*)lx;
        for (int i = tid; i < 6272; i += 768) dst[i] = src[i];
    }
    __syncthreads();

    const int o = tid & 31, r = tid >> 5;
    float acc[24];
#pragma unroll
    for (int j = 0; j < 24; j++) acc[j] = 0.f;

    for (int c = 0; c < 32; c++) {
        // 25 weight regs, coalesced/broadcast single-line loads
        float wv[25];
        const float* wp = wt2 + c * 800 + o;
#pragma unroll
        for (int k = 0; k < 25; k++) wv[k] = wp[k * 32];

#pragma unroll
        for (int kh = 0; kh < 5; kh++) {
            const float4* xr = (const float4*)&lx[(c * 28 + r + kh) * 28];
            float xw[28];
#pragma unroll
            for (int i = 0; i < 7; i++) {
                float4 v = xr[i];
                xw[4 * i + 0] = v.x; xw[4 * i + 1] = v.y;
                xw[4 * i + 2] = v.z; xw[4 * i + 3] = v.w;
            }
#pragma unroll
            for (int kw = 0; kw < 5; kw++)
#pragma unroll
                for (int j = 0; j < 24; j++)
                    acc[j] += fabsf(xw[j + kw] - wv[kh * 5 + kw]);
        }
    }

    // PReLU + horizontal pool (max over col-octets)
    const float alpha = a2v[0];
#pragma unroll
    for (int jj = 0; jj < 3; jj++) {
        float m = -1e30f;
#pragma unroll
        for (int k = 0; k < 8; k++) {
            float v = -acc[jj * 8 + k];
            v = (v >= 0.f) ? v : alpha * v;
            m = fmaxf(m, v);
        }
        lrm[(o * 24 + r) * 3 + jj] = m;
    }
    __syncthreads();

    // vertical pool: max over row-octets -> pooled[o][i][j]
    if (tid < 288) {
        int oo = tid / 9, rem = tid % 9, ii = rem / 3, jj = rem % 3;
        float m = -1e30f;
#pragma unroll
        for (int k = 0; k < 8; k++)
            m = fmaxf(m, lrm[(oo * 24 + ii * 8 + k) * 3 + jj]);
        lpool[tid] = m;  // tid == oo*9 + ii*3 + jj
    }
    __syncthreads();

    // FC head: ip1 = prelu(pooled @ ip1_w.T + b), ip2 = ip1 @ ip2_w.T
    if (tid < 64) {
        float f0 = 0.f, f1 = 0.f;
        for (int t = tid; t < 288; t += 64) {
            float p = lpool[t];
            f0 += p * ip1_w[t];
            f1 += p * ip1_w[288 + t];
        }
#pragma unroll
        for (int off = 32; off > 0; off >>= 1) {
            f0 += __shfl_down(f0, off);
            f1 += __shfl_down(f1, off);
        }
        if (tid == 0) {
            float a3 = a3v[0];
            float i0 = f0 + ip1_b[0], i1 = f1 + ip1_b[1];
            i0 = (i0 >= 0.f) ? i0 : a3 * i0;
            i1 = (i1 >= 0.f) ? i1 : a3 * i1;
            dout[b * 2 + 0] = i0;
            dout[b * 2 + 1] = i1;
#pragma unroll
            for (int m = 0; m < 10; m++)
                dout[512 + b * 10 + m] = i0 * ip2_w[m * 2] + i1 * ip2_w[m * 2 + 1];
        }
    }
}

extern "C" void kernel_launch(void* const* d_in, const int* in_sizes, int n_in,
                              void* d_out, int out_size, void* d_ws, size_t ws_size,
                              hipStream_t stream) {
    const float* x     = (const float*)d_in[0];
    const float* w1    = (const float*)d_in[1];
    const float* a1    = (const float*)d_in[2];
    const float* w2    = (const float*)d_in[3];
    const float* a2    = (const float*)d_in[4];
    const float* ip1_w = (const float*)d_in[5];
    const float* ip1_b = (const float*)d_in[6];
    const float* a3    = (const float*)d_in[7];
    const float* ip2_w = (const float*)d_in[8];
    float* out = (float*)d_out;

    char* ws = (char*)d_ws;
    float* wt1   = (float*)(ws);             //   3200 B
    float* wt2   = (float*)(ws + 4096);      // 102400 B
    float* h1pad = (float*)(ws + 131072);    // 25.69 MB

    prep_weights<<<52, 512, 0, stream>>>(w1, w2, wt1, wt2);
    layer1<<<256, 896, 0, stream>>>(x, wt1, a1, h1pad);
    layer2_fused<<<256, 768, 0, stream>>>(h1pad, wt2, a2, ip1_w, ip1_b, a3,
                                          ip2_w, out);
}